// Round 11
// baseline (500.438 us; speedup 1.0000x reference)
//
#include <hip/hip_runtime.h>

// Problem constants
#define S_LEN 256
#define B_SZ  128
#define M_ROWS (S_LEN * B_SZ)          // 32768

typedef __attribute__((ext_vector_type(8))) short bf16x8;
typedef __attribute__((ext_vector_type(4))) float f32x4;

__device__ __forceinline__ unsigned short f2bf(float x) {
    unsigned u = __float_as_uint(x);
    unsigned r = (u + 0x7fffu + ((u >> 16) & 1u)) >> 16;   // RNE
    return (unsigned short)r;
}

__device__ __forceinline__ void gl_lds16(const void* g, void* l) {
    __builtin_amdgcn_global_load_lds(
        (const __attribute__((address_space(1))) unsigned int*)g,
        (__attribute__((address_space(3))) unsigned int*)l,
        16, 0, 0);
}

// ---------------- Pass 1: seq f32 -> bf16 ----------------
__global__ __launch_bounds__(256) void convert_seq(const float* __restrict__ in,
                                                   unsigned short* __restrict__ out,
                                                   long n4) {
    long i = (long)blockIdx.x * blockDim.x + threadIdx.x;
    long stride = (long)gridDim.x * blockDim.x;
    for (; i < n4; i += stride) {
        float4 v = ((const float4*)in)[i];
        ushort4 o;
        o.x = f2bf(v.x); o.y = f2bf(v.y); o.z = f2bf(v.z); o.w = f2bf(v.w);
        ((ushort4*)out)[i] = o;
    }
}

// ---------------- Pass 2: f1,f2 f32 -> bf16 (layer-major) ----------------
__global__ __launch_bounds__(256) void convert_f(const float* __restrict__ f1,
                                                 const float* __restrict__ f2,
                                                 unsigned short* __restrict__ out) {
    int g = blockIdx.x * 256 + threadIdx.x;            // 0..65535 float4 groups
    float4 v = (g < 32768) ? ((const float4*)f1)[g] : ((const float4*)f2)[g - 32768];
    ushort4 o;
    o.x = f2bf(v.x); o.y = f2bf(v.y); o.z = f2bf(v.z); o.w = f2bf(v.w);
    ((ushort4*)out)[g] = o;
}

// ---------------- Pass 3: W [2048][1024] f32 -> Wt [2][1024][2048] bf16 ----------------
__global__ __launch_bounds__(256) void transpose_w(const float* __restrict__ W11,
                                                   const float* __restrict__ W12,
                                                   unsigned short* __restrict__ Wt) {
    const int nt = blockIdx.x, kt = blockIdx.y, layer = blockIdx.z;
    const float* W = layer ? W12 : W11;
    __shared__ float T[64][65];
    const int c = threadIdx.x & 63, r4 = threadIdx.x >> 6;
    const int k0 = kt * 64, n0 = nt * 64;
    #pragma unroll
    for (int p = 0; p < 16; ++p) {
        int r = p * 4 + r4;
        T[r][c] = W[(size_t)(k0 + r) * 1024 + n0 + c];
    }
    __syncthreads();
    unsigned short* Wl = Wt + (size_t)layer * 1024 * 2048;
    #pragma unroll
    for (int p = 0; p < 16; ++p) {
        int n = p * 4 + r4;
        Wl[(size_t)(n0 + n) * 2048 + k0 + c] = f2bf(T[c][n]);
    }
}

// ---------------- Pass 4: c[layer][b][h] = f@W[1024:] + bias  (MFMA 128x128 tile) ----------------
__global__ __launch_bounds__(256) void c_precompute(const unsigned short* __restrict__ fbf, // [2][128][1024]
                                                    const unsigned short* __restrict__ Wt,  // [2][1024][2048]
                                                    const float* __restrict__ b11,
                                                    const float* __restrict__ b12,
                                                    float* __restrict__ cbuf) {            // [2][128][1024]
    __shared__ char smem[32768];
    unsigned short* ldsA = (unsigned short*)smem;            // [128][64]
    unsigned short* ldsB = (unsigned short*)(smem + 16384);  // [128][64]
    const int n0 = blockIdx.x * 128;
    const int layer = blockIdx.y;
    const int tid = threadIdx.x;
    const int w = tid >> 6, l = tid & 63;
    const int wm = w >> 1, wn = w & 1;
    const int lr = l & 15, lg = l >> 4;
    const unsigned short* Af = fbf + (size_t)layer * 128 * 1024;
    const unsigned short* Wl = Wt + (size_t)layer * 1024 * 2048;
    const float* bias = layer ? b12 : b11;

    f32x4 acc[4][4];
    #pragma unroll
    for (int i = 0; i < 4; ++i)
        #pragma unroll
        for (int j = 0; j < 4; ++j)
            #pragma unroll
            for (int e = 0; e < 4; ++e) acc[i][j][e] = 0.f;

    for (int kk = 0; kk < 1024; kk += 64) {
        __syncthreads();
        #pragma unroll
        for (int c = 0; c < 4; ++c) {
            int o = w * 4096 + c * 1024;
            int ob = o + l * 16;
            int row = ob >> 7, kb = ob & 127;
            gl_lds16((const char*)Af + ((size_t)row * 1024 + kk) * 2 + kb, (char*)ldsA + o);
            gl_lds16((const char*)Wl + ((size_t)(n0 + row) * 2048 + 1024 + kk) * 2 + kb, (char*)ldsB + o);
        }
        __syncthreads();
        #pragma unroll
        for (int ks = 0; ks < 2; ++ks) {
            bf16x8 av[4], bv[4];
            #pragma unroll
            for (int i = 0; i < 4; ++i) {
                av[i] = *(const bf16x8*)(ldsA + (wm * 64 + i * 16 + lr) * 64 + ks * 32 + lg * 8);
                bv[i] = *(const bf16x8*)(ldsB + (wn * 64 + i * 16 + lr) * 64 + ks * 32 + lg * 8);
            }
            #pragma unroll
            for (int i = 0; i < 4; ++i)
                #pragma unroll
                for (int j = 0; j < 4; ++j)
                    acc[i][j] = __builtin_amdgcn_mfma_f32_16x16x32_bf16(av[i], bv[j], acc[i][j], 0, 0, 0);
        }
    }
    float* cl = cbuf + (size_t)layer * 128 * 1024;
    #pragma unroll
    for (int i = 0; i < 4; ++i)
        #pragma unroll
        for (int j = 0; j < 4; ++j)
            #pragma unroll
            for (int q = 0; q < 4; ++q) {
                int rr = wm * 64 + i * 16 + lg * 4 + q;
                int hc = n0 + wn * 64 + j * 16 + lr;
                cl[(size_t)rr * 1024 + hc] = acc[i][j][q] + bias[hc];
            }
}

// ================= Pass 5: main fused GEMM =================
// 256x256 tile, BK=64, 16 waves (wave-tile 64x64), 1 block/CU.
// KEY CHANGE vs R9: A-fragments are loaded DIRECTLY global->VGPR (per-lane
// addresses reproduce the LDS fragment mapping exactly); only B goes through
// LDS (dbuf 2 x 32 KB = 64 KB). This halves LDS traffic per K-tile
// (320 KB -> 160 KB incl. staging writes), moving the floor to the MFMA pipe
// (~2480 cyc/K-tile/CU). A is XCD-L2/L1-resident via the affinity decode.
// A-loads are issued BEFORE the B STAGE each K-tile (sched_barrier pinned) so
// compiler vmcnt waits on A do not force the B staging to drain early.
// B LDS layout/swizzle identical to R9 ([256 rows][128 B], x ^= ((x>>3)&0x70),
// verified SQ_LDS_BANK_CONFLICT = 0); ks=1 via offset ^ 64.

__global__ __launch_bounds__(1024, 4) void fused_main(const unsigned short* __restrict__ Abf, // [32768][1024] bf16
                                                      const unsigned short* __restrict__ Wt,  // [2][1024][2048] bf16
                                                      const float* __restrict__ cbuf,         // [2][128][1024]
                                                      const float* __restrict__ W21,
                                                      const float* __restrict__ W22,
                                                      float* __restrict__ sbufp) {            // [8][32768]
    __shared__ char smem[65536];   // 2 bufs x B 32 KB
    const int bid = blockIdx.x;
    const int xcd = bid & 7;
    const int idx = bid >> 3;                    // 0..127
    const int mtq = (idx & 3) + 4 * (idx >> 5);  // 0..15
    const int g   = (idx >> 2) & 7;              // layer*4 + nt
    const int mt  = xcd + 8 * mtq;               // 0..127
    const int layer = g >> 2;
    const int nt    = g & 3;
    const int n0 = nt * 256;

    const int tid = threadIdx.x;
    const int w = tid >> 6, l = tid & 63;
    const int wm = w >> 2, wn = w & 3;  // 4 M-quarters x 4 N-quarters (wave tile 64x64)
    const int lr = l & 15, lg = l >> 4;

    const char* Ag = (const char*)Abf + (size_t)mt * 256 * 2048;                          // row stride 2048 B
    const char* Bg = (const char*)(Wt + (size_t)layer * 1024 * 2048) + (size_t)n0 * 4096; // row stride 4096 B

    // B staging: 32 KB per K-tile = 2 gl_lds/thread (rows 0-127, 128-255).
    // Linear dest + inverse-swizzled global source (R9-verified).
    const int dloc = tid * 16;
    const int gsw  = dloc ^ ((dloc >> 3) & 0x70);
    const char* srcB = Bg + (size_t)(gsw >> 7) * 4096 + (gsw & 127);
    const int dstT = w * 1024;   // wave-uniform LDS base (HW adds lane*16)

    // B fragment LDS offsets (swizzled, ks=0); ks=1 = offset ^ 64
    const int xr = (lr & 7) << 4;
    int offB[4];
    #pragma unroll
    for (int i = 0; i < 4; ++i)
        offB[i] = (wn * 64 + i * 16 + lr) * 128 + ((lg * 16) ^ xr);

    // A per-lane global base: row = wm*64 + lr, k-byte = lg*16; per-i offset
    // i*16 rows = i*32768 B; per-K-tile t*128 B; per-ks +64 B.
    const char* aLane = Ag + (size_t)(wm * 64 + lr) * 2048 + (size_t)(lg * 16);

    f32x4 acc[4][4];
    #pragma unroll
    for (int i = 0; i < 4; ++i)
        #pragma unroll
        for (int j = 0; j < 4; ++j)
            #pragma unroll
            for (int e = 0; e < 4; ++e) acc[i][j][e] = 0.f;

#define STAGEB(t, bi) do {                                              \
        char* d_ = smem + (bi) * 32768;                                 \
        gl_lds16(srcB + (size_t)(t) * 128,              d_ +         dstT); \
        gl_lds16(srcB + (size_t)(t) * 128 + 128 * 4096, d_ + 16384 + dstT); \
    } while (0)

#define KTILE(t, bi) do {                                               \
        bf16x8 av_[8];                                                  \
        _Pragma("unroll")                                               \
        for (int i_ = 0; i_ < 4; ++i_) {                                \
            const char* ap_ = aLane + i_ * 32768 + (size_t)(t) * 128;   \
            av_[i_ * 2 + 0] = *(const bf16x8*)(ap_);                    \
            av_[i_ * 2 + 1] = *(const bf16x8*)(ap_ + 64);               \
        }                                                               \
        __builtin_amdgcn_sched_barrier(0);  /* keep A-loads older than gl_lds */ \
        if ((t) < 15) STAGEB((t) + 1, (bi) ^ 1);                        \
        const char* Bb_ = smem + (bi) * 32768;                          \
        _Pragma("unroll")                                               \
        for (int ks_ = 0; ks_ < 2; ++ks_) {                             \
            bf16x8 bv_[4];                                              \
            _Pragma("unroll")                                           \
            for (int j_ = 0; j_ < 4; ++j_)                              \
                bv_[j_] = *(const bf16x8*)(Bb_ + (offB[j_] ^ (ks_ * 64))); \
            _Pragma("unroll")                                           \
            for (int i_ = 0; i_ < 4; ++i_)                              \
                _Pragma("unroll")                                       \
                for (int j_ = 0; j_ < 4; ++j_)                          \
                    acc[i_][j_] = __builtin_amdgcn_mfma_f32_16x16x32_bf16( \
                        av_[i_ * 2 + ks_], bv_[j_], acc[i_][j_], 0, 0, 0); \
        }                                                               \
    } while (0)

#define WAITBAR() do {                                                  \
        __builtin_amdgcn_sched_barrier(0);                              \
        asm volatile("s_waitcnt vmcnt(0)" ::: "memory");                \
        __builtin_amdgcn_sched_barrier(0);                              \
        __builtin_amdgcn_s_barrier();                                   \
        __builtin_amdgcn_sched_barrier(0);                              \
    } while (0)

    // prologue: stage B tile 0
    STAGEB(0, 0);
    WAITBAR();

    // main loop: 16 K-tiles, unrolled x2 for static buffer indices
    for (int tt = 0; tt < 16; tt += 2) {
        KTILE(tt, 0);     WAITBAR();
        KTILE(tt + 1, 1); WAITBAR();
    }

#undef STAGEB
#undef KTILE
#undef WAITBAR

    // ---- epilogue: z = acc + c, h = tanh(z), dot with W21/W22, reduce ----
    const float* cl = cbuf + (size_t)layer * 131072;
    const float* W2 = layer ? W22 : W21;
    float w2v[4];
    #pragma unroll
    for (int j = 0; j < 4; ++j) w2v[j] = W2[n0 + wn * 64 + j * 16 + lr];
    float* red = (float*)smem;   // [256][4]  (final loop barrier fences reuse)
    #pragma unroll
    for (int i = 0; i < 4; ++i) {
        #pragma unroll
        for (int q = 0; q < 4; ++q) {
            int wrow = wm * 64 + i * 16 + lg * 4 + q;    // 0..255 within M-tile
            int brow = wrow & 127;                        // b index
            float p = 0.f;
            #pragma unroll
            for (int j = 0; j < 4; ++j) {
                int col = n0 + wn * 64 + j * 16 + lr;
                float z = acc[i][j][q] + cl[(size_t)brow * 1024 + col];
                float e = __expf(2.f * z);
                p += (1.f - 2.f / (e + 1.f)) * w2v[j];
            }
            p += __shfl_xor(p, 1);
            p += __shfl_xor(p, 2);
            p += __shfl_xor(p, 4);
            p += __shfl_xor(p, 8);
            if (lr == 0) red[wrow * 4 + wn] = p;
        }
    }
    __syncthreads();
    if (tid < 256) {
        float v = red[tid * 4 + 0] + red[tid * 4 + 1] + red[tid * 4 + 2] + red[tid * 4 + 3];
        sbufp[(size_t)g * M_ROWS + (size_t)mt * 256 + tid] = v;
    }
}

// ---------------- Pass 6: softmax over s -> coef ----------------
__device__ __forceinline__ float block_max(float v, float* lds) {
    #pragma unroll
    for (int m = 32; m; m >>= 1) v = fmaxf(v, __shfl_xor(v, m));
    if ((threadIdx.x & 63) == 0) lds[threadIdx.x >> 6] = v;
    __syncthreads();
    v = fmaxf(fmaxf(lds[0], lds[1]), fmaxf(lds[2], lds[3]));
    __syncthreads();
    return v;
}
__device__ __forceinline__ float block_sum(float v, float* lds) {
    #pragma unroll
    for (int m = 32; m; m >>= 1) v += __shfl_xor(v, m);
    if ((threadIdx.x & 63) == 0) lds[threadIdx.x >> 6] = v;
    __syncthreads();
    v = lds[0] + lds[1] + lds[2] + lds[3];
    __syncthreads();
    return v;
}

__global__ __launch_bounds__(256) void coef_kernel(const float* __restrict__ sbufp,
                                                   float* __restrict__ coef) {
    __shared__ float lds[4];
    const int b = blockIdx.x, s = threadIdx.x;
    float v1 = 0.f, v2 = 0.f;
    #pragma unroll
    for (int nt = 0; nt < 4; ++nt) {
        v1 += sbufp[(size_t)nt * M_ROWS + (size_t)s * 128 + b];
        v2 += sbufp[(size_t)(4 + nt) * M_ROWS + (size_t)s * 128 + b];
    }
    float m1 = block_max(v1, lds);
    float e1 = expf(v1 - m1);
    float S1 = block_sum(e1, lds);
    float m2 = block_max(v2, lds);
    float e2 = expf(v2 - m2);
    float S2 = block_sum(e2, lds);
    coef[(size_t)s * 128 + b] = (e1 / S1 + e2 / S2) * (0.5f / (float)S_LEN);
}

// ---------------- Pass 7: out[b][d] = sum_s coef[s][b] * seq[s][b][d] ----------------
// Atomic-free: each thread owns one output element, loops all 256 s.
__global__ __launch_bounds__(256) void final_kernel(const float* __restrict__ seq,
                                                    const float* __restrict__ coef,
                                                    float* __restrict__ out) {
    const int b = blockIdx.x, dq = blockIdx.y;
    const int d = dq * 256 + threadIdx.x;
    float a = 0.f;
    #pragma unroll 8
    for (int s = 0; s < 256; ++s) {
        a += coef[(size_t)s * 128 + b] * seq[(size_t)(s * 128 + b) * 1024 + d];
    }
    out[(size_t)b * 1024 + d] = a;
}

extern "C" void kernel_launch(void* const* d_in, const int* in_sizes, int n_in,
                              void* d_out, int out_size, void* d_ws, size_t ws_size,
                              hipStream_t stream) {
    const float* feature1 = (const float*)d_in[0];   // [128,1024]
    const float* feature2 = (const float*)d_in[1];   // [128,1024]
    const float* seq      = (const float*)d_in[2];   // [256,128,1024]
    const float* W11      = (const float*)d_in[3];   // [2048,1024]
    const float* b11      = (const float*)d_in[4];
    const float* W12      = (const float*)d_in[5];
    const float* b12      = (const float*)d_in[6];
    const float* W21      = (const float*)d_in[7];   // [1024,1]
    const float* W22      = (const float*)d_in[9];
    float* out = (float*)d_out;

    char* ws = (char*)d_ws;
    unsigned short* Abf   = (unsigned short*)(ws + 0);                  // 67108864 B
    unsigned short* Wt    = (unsigned short*)(ws + 67108864);           //  8388608 B
    unsigned short* fbf   = (unsigned short*)(ws + 75497472);           //   524288 B
    float*          cbuf  = (float*)(ws + 76021760);                    //  1048576 B
    float*          sbufp = (float*)(ws + 77070336);                    //  1048576 B  [8][32768]
    float*          coef  = (float*)(ws + 78118912);                    //   131072 B

    convert_seq<<<2048, 256, 0, stream>>>(seq, Abf, (long)M_ROWS * 1024 / 4);
    convert_f<<<256, 256, 0, stream>>>(feature1, feature2, fbf);
    transpose_w<<<dim3(16, 32, 2), 256, 0, stream>>>(W11, W12, Wt);
    c_precompute<<<dim3(8, 2), 256, 0, stream>>>(fbf, Wt, b11, b12, cbuf);
    fused_main<<<1024, 1024, 0, stream>>>(Abf, Wt, cbuf, W21, W22, sbufp);
    coef_kernel<<<128, 256, 0, stream>>>(sbufp, coef);
    final_kernel<<<dim3(128, 4), 256, 0, stream>>>(seq, coef, out);
}

// Round 12
// 369.682 us; speedup vs baseline: 1.3537x; 1.3537x over previous
//
#include <hip/hip_runtime.h>

// Problem constants
#define S_LEN 256
#define B_SZ  128
#define M_ROWS (S_LEN * B_SZ)          // 32768

typedef __attribute__((ext_vector_type(8))) short bf16x8;
typedef __attribute__((ext_vector_type(4))) float f32x4;

__device__ __forceinline__ unsigned short f2bf(float x) {
    unsigned u = __float_as_uint(x);
    unsigned r = (u + 0x7fffu + ((u >> 16) & 1u)) >> 16;   // RNE
    return (unsigned short)r;
}

__device__ __forceinline__ void gl_lds16(const void* g, void* l) {
    __builtin_amdgcn_global_load_lds(
        (const __attribute__((address_space(1))) unsigned int*)g,
        (__attribute__((address_space(3))) unsigned int*)l,
        16, 0, 0);
}

// ---------------- Pass 1: seq f32 -> bf16, FRAGMENT-MAJOR ----------------
// Apre layout (16B chunks): addr16 = ((((mt*16 + kt)*16 + rb)*2 + ks)*4 + lg)*16 + lr
//   element: row = mt*256 + rb*16 + lr (global M row = s*128+b), k = kt*64 + ks*32 + lg*8 .. +7
// A wave's MFMA A-fragment load is then base + lane*16 (fully coalesced 1 KB).
__global__ __launch_bounds__(256) void convert_seqA(const float* __restrict__ seq,
                                                    unsigned short* __restrict__ Apre) {
    int gid = blockIdx.x * 256 + threadIdx.x;     // 0 .. 4M-1 (one 16B chunk each)
    int x = gid;
    const int lr = x & 15;  x >>= 4;
    const int lg = x & 3;   x >>= 2;
    const int ks = x & 1;   x >>= 1;
    const int rb = x & 15;  x >>= 4;
    const int kt = x & 15;  x >>= 4;
    const int mt = x;                              // 0..127
    const int row = mt * 256 + rb * 16 + lr;
    const int k   = kt * 64 + ks * 32 + lg * 8;
    const float* p = seq + (size_t)row * 1024 + k;
    float4 v0 = *(const float4*)(p);
    float4 v1 = *(const float4*)(p + 4);
    bf16x8 o;
    o[0] = (short)f2bf(v0.x); o[1] = (short)f2bf(v0.y);
    o[2] = (short)f2bf(v0.z); o[3] = (short)f2bf(v0.w);
    o[4] = (short)f2bf(v1.x); o[5] = (short)f2bf(v1.y);
    o[6] = (short)f2bf(v1.z); o[7] = (short)f2bf(v1.w);
    ((bf16x8*)Apre)[gid] = o;
}

// ---------------- Pass 2: f1,f2 f32 -> bf16 (layer-major) ----------------
__global__ __launch_bounds__(256) void convert_f(const float* __restrict__ f1,
                                                 const float* __restrict__ f2,
                                                 unsigned short* __restrict__ out) {
    int g = blockIdx.x * 256 + threadIdx.x;            // 0..65535 float4 groups
    float4 v = (g < 32768) ? ((const float4*)f1)[g] : ((const float4*)f2)[g - 32768];
    ushort4 o;
    o.x = f2bf(v.x); o.y = f2bf(v.y); o.z = f2bf(v.z); o.w = f2bf(v.w);
    ((ushort4*)out)[g] = o;
}

// ---------------- Pass 3: W [2048][1024] f32 -> Wt [2][1024][2048] bf16 ----------------
__global__ __launch_bounds__(256) void transpose_w(const float* __restrict__ W11,
                                                   const float* __restrict__ W12,
                                                   unsigned short* __restrict__ Wt) {
    const int nt = blockIdx.x, kt = blockIdx.y, layer = blockIdx.z;
    const float* W = layer ? W12 : W11;
    __shared__ float T[64][65];
    const int c = threadIdx.x & 63, r4 = threadIdx.x >> 6;
    const int k0 = kt * 64, n0 = nt * 64;
    #pragma unroll
    for (int p = 0; p < 16; ++p) {
        int r = p * 4 + r4;
        T[r][c] = W[(size_t)(k0 + r) * 1024 + n0 + c];
    }
    __syncthreads();
    unsigned short* Wl = Wt + (size_t)layer * 1024 * 2048;
    #pragma unroll
    for (int p = 0; p < 16; ++p) {
        int n = p * 4 + r4;
        Wl[(size_t)(n0 + n) * 2048 + k0 + c] = f2bf(T[c][n]);
    }
}

// ---------------- Pass 4: c[layer][b][h] = f@W[1024:] + bias  (MFMA 128x128 tile) ----------------
__global__ __launch_bounds__(256) void c_precompute(const unsigned short* __restrict__ fbf, // [2][128][1024]
                                                    const unsigned short* __restrict__ Wt,  // [2][1024][2048]
                                                    const float* __restrict__ b11,
                                                    const float* __restrict__ b12,
                                                    float* __restrict__ cbuf) {            // [2][128][1024]
    __shared__ char smem[32768];
    unsigned short* ldsA = (unsigned short*)smem;            // [128][64]
    unsigned short* ldsB = (unsigned short*)(smem + 16384);  // [128][64]
    const int n0 = blockIdx.x * 128;
    const int layer = blockIdx.y;
    const int tid = threadIdx.x;
    const int w = tid >> 6, l = tid & 63;
    const int wm = w >> 1, wn = w & 1;
    const int lr = l & 15, lg = l >> 4;
    const unsigned short* Af = fbf + (size_t)layer * 128 * 1024;
    const unsigned short* Wl = Wt + (size_t)layer * 1024 * 2048;
    const float* bias = layer ? b12 : b11;

    f32x4 acc[4][4];
    #pragma unroll
    for (int i = 0; i < 4; ++i)
        #pragma unroll
        for (int j = 0; j < 4; ++j)
            #pragma unroll
            for (int e = 0; e < 4; ++e) acc[i][j][e] = 0.f;

    for (int kk = 0; kk < 1024; kk += 64) {
        __syncthreads();
        #pragma unroll
        for (int c = 0; c < 4; ++c) {
            int o = w * 4096 + c * 1024;
            int ob = o + l * 16;
            int row = ob >> 7, kb = ob & 127;
            gl_lds16((const char*)Af + ((size_t)row * 1024 + kk) * 2 + kb, (char*)ldsA + o);
            gl_lds16((const char*)Wl + ((size_t)(n0 + row) * 2048 + 1024 + kk) * 2 + kb, (char*)ldsB + o);
        }
        __syncthreads();
        #pragma unroll
        for (int ks = 0; ks < 2; ++ks) {
            bf16x8 av[4], bv[4];
            #pragma unroll
            for (int i = 0; i < 4; ++i) {
                av[i] = *(const bf16x8*)(ldsA + (wm * 64 + i * 16 + lr) * 64 + ks * 32 + lg * 8);
                bv[i] = *(const bf16x8*)(ldsB + (wn * 64 + i * 16 + lr) * 64 + ks * 32 + lg * 8);
            }
            #pragma unroll
            for (int i = 0; i < 4; ++i)
                #pragma unroll
                for (int j = 0; j < 4; ++j)
                    acc[i][j] = __builtin_amdgcn_mfma_f32_16x16x32_bf16(av[i], bv[j], acc[i][j], 0, 0, 0);
        }
    }
    float* cl = cbuf + (size_t)layer * 128 * 1024;
    #pragma unroll
    for (int i = 0; i < 4; ++i)
        #pragma unroll
        for (int j = 0; j < 4; ++j)
            #pragma unroll
            for (int q = 0; q < 4; ++q) {
                int rr = wm * 64 + i * 16 + lg * 4 + q;
                int hc = n0 + wn * 64 + j * 16 + lr;
                cl[(size_t)rr * 1024 + hc] = acc[i][j][q] + bias[hc];
            }
}

// ================= Pass 5: main fused GEMM =================
// 256x256 tile, BK=64, 16 waves (wave-tile 64x64), 1 block/CU.
// A: DIRECT global->VGPR from fragment-major Apre — coalesced (base + lane*16),
//    half-tile prefetch: A(t,ks1) issued at tile start, A(t+1,ks0) mid-tile.
//    Register cost 32 VGPR (A0/A1, overwritten in place after their MFMAs issue).
// B: LDS dbuf 2 x 32 KB (R9 layout+swizzle, SQ_LDS_BANK_CONFLICT=0 verified).
// LDS traffic/K-tile: 320 KB -> 160 KB => MFMA pipe (~2480 cyc) becomes floor.
// Pre-barrier vmcnt(4): forces B-stage(t+1) complete, leaves A(t+1,ks0) in
// flight. A-use waits are compiler-derived (exact counted, no drain).
// One barrier per K-tile (16 total). XCD decode as R8 (FETCH 115 MB).

__global__ __launch_bounds__(1024, 4) void fused_main(const unsigned short* __restrict__ Apre, // frag-major, 64 MB
                                                      const unsigned short* __restrict__ Wt,   // [2][1024][2048] bf16
                                                      const float* __restrict__ cbuf,          // [2][128][1024]
                                                      const float* __restrict__ W21,
                                                      const float* __restrict__ W22,
                                                      float* __restrict__ sbufp) {             // [8][32768]
    __shared__ char smem[65536];   // 2 bufs x B 32 KB
    const int bid = blockIdx.x;
    const int xcd = bid & 7;
    const int idx = bid >> 3;                    // 0..127
    const int mtq = (idx & 3) + 4 * (idx >> 5);  // 0..15
    const int g   = (idx >> 2) & 7;              // layer*4 + nt
    const int mt  = xcd + 8 * mtq;               // 0..127
    const int layer = g >> 2;
    const int nt    = g & 3;
    const int n0 = nt * 256;

    const int tid = threadIdx.x;
    const int w = tid >> 6, l = tid & 63;
    const int wm = w >> 2, wn = w & 3;  // 4 M-quarters x 4 N-quarters (wave tile 64x64)
    const int lr = l & 15, lg = l >> 4;

    const char* Bg = (const char*)(Wt + (size_t)layer * 1024 * 2048) + (size_t)n0 * 4096; // row stride 4096 B

    // A fragment pointer: chunk addr = mt*524288 + kt*32768 + rb*2048 + ks*1024 + l*16
    // (rb = wm*4 + i). aT advances by 32768 per K-tile.
    const char* aT = (const char*)Apre + (size_t)mt * 524288
                   + (size_t)(wm * 4) * 2048 + (size_t)l * 16;

    // B staging (R9-verified): 32 KB per K-tile = 2 gl_lds/thread.
    const int dloc = tid * 16;
    const int gsw  = dloc ^ ((dloc >> 3) & 0x70);
    const char* srcB = Bg + (size_t)(gsw >> 7) * 4096 + (gsw & 127);
    const int dstT = w * 1024;   // wave-uniform LDS base (HW adds lane*16)

    // B fragment LDS offsets (swizzled, ks=0); ks=1 = offset ^ 64
    const int xr = (lr & 7) << 4;
    int offB[4];
    #pragma unroll
    for (int i = 0; i < 4; ++i)
        offB[i] = (wn * 64 + i * 16 + lr) * 128 + ((lg * 16) ^ xr);

    f32x4 acc[4][4];
    #pragma unroll
    for (int i = 0; i < 4; ++i)
        #pragma unroll
        for (int j = 0; j < 4; ++j)
            #pragma unroll
            for (int e = 0; e < 4; ++e) acc[i][j][e] = 0.f;

    bf16x8 A0[4], A1[4];

#define STAGEB(t, bi) do {                                              \
        char* d_ = smem + (bi) * 32768;                                 \
        gl_lds16(srcB + (size_t)(t) * 128,              d_ +         dstT); \
        gl_lds16(srcB + (size_t)(t) * 128 + 128 * 4096, d_ + 16384 + dstT); \
    } while (0)

#define KT(t, bi) do {                                                  \
        /* issue A(t, ks1) */                                           \
        { const char* ap_ = aT + 1024;                                  \
          _Pragma("unroll")                                             \
          for (int i_ = 0; i_ < 4; ++i_)                                \
              A1[i_] = *(const bf16x8*)(ap_ + i_ * 2048); }             \
        __builtin_amdgcn_sched_barrier(0);                              \
        /* B ks0 reads + MFMA ks0 (A0 prefetched last tile) */          \
        { const char* Bb_ = smem + (bi) * 32768;                        \
          bf16x8 bv_[4];                                                \
          _Pragma("unroll")                                             \
          for (int j_ = 0; j_ < 4; ++j_)                                \
              bv_[j_] = *(const bf16x8*)(Bb_ + offB[j_]);               \
          _Pragma("unroll")                                             \
          for (int i_ = 0; i_ < 4; ++i_)                                \
              _Pragma("unroll")                                         \
              for (int j_ = 0; j_ < 4; ++j_)                            \
                  acc[i_][j_] = __builtin_amdgcn_mfma_f32_16x16x32_bf16(\
                      A0[i_], bv_[j_], acc[i_][j_], 0, 0, 0); }         \
        __builtin_amdgcn_sched_barrier(0);                              \
        /* stage B(t+1) + issue A(t+1, ks0) */                          \
        if ((t) < 15) {                                                 \
            STAGEB((t) + 1, (bi) ^ 1);                                  \
            const char* an_ = aT + 32768;                               \
            _Pragma("unroll")                                           \
            for (int i_ = 0; i_ < 4; ++i_)                              \
                A0[i_] = *(const bf16x8*)(an_ + i_ * 2048);             \
        }                                                               \
        __builtin_amdgcn_sched_barrier(0);                              \
        /* B ks1 reads + MFMA ks1 */                                    \
        { const char* Bb_ = smem + (bi) * 32768;                        \
          bf16x8 bv_[4];                                                \
          _Pragma("unroll")                                             \
          for (int j_ = 0; j_ < 4; ++j_)                                \
              bv_[j_] = *(const bf16x8*)(Bb_ + (offB[j_] ^ 64));        \
          _Pragma("unroll")                                             \
          for (int i_ = 0; i_ < 4; ++i_)                                \
              _Pragma("unroll")                                         \
              for (int j_ = 0; j_ < 4; ++j_)                            \
                  acc[i_][j_] = __builtin_amdgcn_mfma_f32_16x16x32_bf16(\
                      A1[i_], bv_[j_], acc[i_][j_], 0, 0, 0); }         \
        __builtin_amdgcn_sched_barrier(0);                              \
        asm volatile("s_waitcnt vmcnt(4)" ::: "memory");                \
        __builtin_amdgcn_sched_barrier(0);                              \
        __builtin_amdgcn_s_barrier();                                   \
        __builtin_amdgcn_sched_barrier(0);                              \
        aT += 32768;                                                    \
    } while (0)

    // prologue: stage B(0); issue A(0, ks0); drain stage only (A may fly)
    STAGEB(0, 0);
    {
        _Pragma("unroll")
        for (int i_ = 0; i_ < 4; ++i_)
            A0[i_] = *(const bf16x8*)(aT + i_ * 2048);
    }
    __builtin_amdgcn_sched_barrier(0);
    asm volatile("s_waitcnt vmcnt(4)" ::: "memory");
    __builtin_amdgcn_sched_barrier(0);
    __builtin_amdgcn_s_barrier();
    __builtin_amdgcn_sched_barrier(0);

    for (int tt = 0; tt < 16; tt += 2) {
        KT(tt, 0);
        KT(tt + 1, 1);
    }

#undef STAGEB
#undef KT

    // ---- epilogue: z = acc + c, h = tanh(z), dot with W21/W22, reduce ----
    const float* cl = cbuf + (size_t)layer * 131072;
    const float* W2 = layer ? W22 : W21;
    float w2v[4];
    #pragma unroll
    for (int j = 0; j < 4; ++j) w2v[j] = W2[n0 + wn * 64 + j * 16 + lr];
    float* red = (float*)smem;   // [256][4]  (final loop barrier fences reuse)
    #pragma unroll
    for (int i = 0; i < 4; ++i) {
        #pragma unroll
        for (int q = 0; q < 4; ++q) {
            int wrow = wm * 64 + i * 16 + lg * 4 + q;    // 0..255 within M-tile
            int brow = wrow & 127;                        // b index
            float p = 0.f;
            #pragma unroll
            for (int j = 0; j < 4; ++j) {
                int col = n0 + wn * 64 + j * 16 + lr;
                float z = acc[i][j][q] + cl[(size_t)brow * 1024 + col];
                float e = __expf(2.f * z);
                p += (1.f - 2.f / (e + 1.f)) * w2v[j];
            }
            p += __shfl_xor(p, 1);
            p += __shfl_xor(p, 2);
            p += __shfl_xor(p, 4);
            p += __shfl_xor(p, 8);
            if (lr == 0) red[wrow * 4 + wn] = p;
        }
    }
    __syncthreads();
    if (tid < 256) {
        float v = red[tid * 4 + 0] + red[tid * 4 + 1] + red[tid * 4 + 2] + red[tid * 4 + 3];
        sbufp[(size_t)g * M_ROWS + (size_t)mt * 256 + tid] = v;
    }
}

// ---------------- Pass 6: softmax over s -> coef ----------------
__device__ __forceinline__ float block_max(float v, float* lds) {
    #pragma unroll
    for (int m = 32; m; m >>= 1) v = fmaxf(v, __shfl_xor(v, m));
    if ((threadIdx.x & 63) == 0) lds[threadIdx.x >> 6] = v;
    __syncthreads();
    v = fmaxf(fmaxf(lds[0], lds[1]), fmaxf(lds[2], lds[3]));
    __syncthreads();
    return v;
}
__device__ __forceinline__ float block_sum(float v, float* lds) {
    #pragma unroll
    for (int m = 32; m; m >>= 1) v += __shfl_xor(v, m);
    if ((threadIdx.x & 63) == 0) lds[threadIdx.x >> 6] = v;
    __syncthreads();
    v = lds[0] + lds[1] + lds[2] + lds[3];
    __syncthreads();
    return v;
}

__global__ __launch_bounds__(256) void coef_kernel(const float* __restrict__ sbufp,
                                                   float* __restrict__ coef) {
    __shared__ float lds[4];
    const int b = blockIdx.x, s = threadIdx.x;
    float v1 = 0.f, v2 = 0.f;
    #pragma unroll
    for (int nt = 0; nt < 4; ++nt) {
        v1 += sbufp[(size_t)nt * M_ROWS + (size_t)s * 128 + b];
        v2 += sbufp[(size_t)(4 + nt) * M_ROWS + (size_t)s * 128 + b];
    }
    float m1 = block_max(v1, lds);
    float e1 = expf(v1 - m1);
    float S1 = block_sum(e1, lds);
    float m2 = block_max(v2, lds);
    float e2 = expf(v2 - m2);
    float S2 = block_sum(e2, lds);
    coef[(size_t)s * 128 + b] = (e1 / S1 + e2 / S2) * (0.5f / (float)S_LEN);
}

// ---------------- Pass 7: out[b][d] = sum_s coef[s][b] * seq[s][b][d] ----------------
// Atomic-free: each thread owns one output element, loops all 256 s.
__global__ __launch_bounds__(256) void final_kernel(const float* __restrict__ seq,
                                                    const float* __restrict__ coef,
                                                    float* __restrict__ out) {
    const int b = blockIdx.x, dq = blockIdx.y;
    const int d = dq * 256 + threadIdx.x;
    float a = 0.f;
    #pragma unroll 8
    for (int s = 0; s < 256; ++s) {
        a += coef[(size_t)s * 128 + b] * seq[(size_t)(s * 128 + b) * 1024 + d];
    }
    out[(size_t)b * 1024 + d] = a;
}

extern "C" void kernel_launch(void* const* d_in, const int* in_sizes, int n_in,
                              void* d_out, int out_size, void* d_ws, size_t ws_size,
                              hipStream_t stream) {
    const float* feature1 = (const float*)d_in[0];   // [128,1024]
    const float* feature2 = (const float*)d_in[1];   // [128,1024]
    const float* seq      = (const float*)d_in[2];   // [256,128,1024]
    const float* W11      = (const float*)d_in[3];   // [2048,1024]
    const float* b11      = (const float*)d_in[4];
    const float* W12      = (const float*)d_in[5];
    const float* b12      = (const float*)d_in[6];
    const float* W21      = (const float*)d_in[7];   // [1024,1]
    const float* W22      = (const float*)d_in[9];
    float* out = (float*)d_out;

    char* ws = (char*)d_ws;
    unsigned short* Apre  = (unsigned short*)(ws + 0);                  // 67108864 B (frag-major)
    unsigned short* Wt    = (unsigned short*)(ws + 67108864);           //  8388608 B
    unsigned short* fbf   = (unsigned short*)(ws + 75497472);           //   524288 B
    float*          cbuf  = (float*)(ws + 76021760);                    //  1048576 B
    float*          sbufp = (float*)(ws + 77070336);                    //  1048576 B  [8][32768]
    float*          coef  = (float*)(ws + 78118912);                    //   131072 B

    convert_seqA<<<16384, 256, 0, stream>>>(seq, Apre);
    convert_f<<<256, 256, 0, stream>>>(feature1, feature2, fbf);
    transpose_w<<<dim3(16, 32, 2), 256, 0, stream>>>(W11, W12, Wt);
    c_precompute<<<dim3(8, 2), 256, 0, stream>>>(fbf, Wt, b11, b12, cbuf);
    fused_main<<<1024, 1024, 0, stream>>>(Apre, Wt, cbuf, W21, W22, sbufp);
    coef_kernel<<<128, 256, 0, stream>>>(sbufp, coef);
    final_kernel<<<dim3(128, 4), 256, 0, stream>>>(seq, coef, out);
}